// Round 6
// baseline (746.639 us; speedup 1.0000x reference)
//
#include <hip/hip_runtime.h>
#include <math.h>

// ---------------- problem constants (fixed by setup_inputs) ----------------
#define B_    2
#define Q_    19947
#define E_    256
#define H_    8
#define D_    32
#define L_    4
#define P_    4

typedef _Float16 f16_t;
typedef f16_t f16x8 __attribute__((ext_vector_type(8)));
typedef f16_t f16x4 __attribute__((ext_vector_type(4)));
typedef float f32x4 __attribute__((ext_vector_type(4)));

// ---------------------------------------------------------------------------
// Weight transpose + fp16 convert + MFMA-fragment-order swizzle.
// Input  fp32 [K=256][N].  Output f16 in fragment order:
//   n -> (nf = n>>4, l16 = n&15),  k -> (kf = k>>5, quad = (k>>3)&3, e = k&7)
//   elem index = (nf*8 + kf)*512 + (quad*16 + l16)*8 + e
// so a wave (lane = quad*16+l16) loading fragment (nf,kf) reads 512
// consecutive f16 = 1 KB fully coalesced (16 B per lane at base+lane*16).
// z: 0=w_val->WtV(256) 1=w_off->WtQ(256) 2=w_attn->WtQ+64K(128) 3=w_out->WtO(256)
// ---------------------------------------------------------------------------
__global__ __launch_bounds__(256)
void transpose_all(const float* __restrict__ w_val, const float* __restrict__ w_off,
                   const float* __restrict__ w_attn, const float* __restrict__ w_out,
                   f16_t* __restrict__ WtV, f16_t* __restrict__ WtQ,
                   f16_t* __restrict__ WtO)
{
    const float* in; f16_t* out; int N;
    switch (blockIdx.z) {
        case 0:  in = w_val;  out = WtV;             N = 256; break;
        case 1:  in = w_off;  out = WtQ;             N = 256; break;
        case 2:  in = w_attn; out = WtQ + 256 * 256; N = 128; break;
        default: in = w_out;  out = WtO;             N = 256; break;
    }
    const int nt = blockIdx.x * 32;
    if (nt >= N) return;
    const int kt = blockIdx.y * 32;          // k-tile (multiple of 32 -> kf fixed)

    __shared__ float tile[32][33];
    const int x  = threadIdx.x & 31;
    const int y0 = threadIdx.x >> 5;          // 0..7
    #pragma unroll
    for (int p = 0; p < 4; ++p)
        tile[y0 + p * 8][x] = in[(size_t)(kt + y0 + p * 8) * N + nt + x];
    __syncthreads();
    const int kf = kt >> 5;
    #pragma unroll
    for (int p = 0; p < 4; ++p) {
        const int n    = nt + y0 + p * 8;
        const int nf   = n >> 4, l16 = n & 15;
        const int quad = (x >> 3) & 3, e = x & 7;
        out[(size_t)(nf * 8 + kf) * 512 + (quad * 16 + l16) * 8 + e]
            = (f16_t)tile[x][y0 + p * 8];
    }
}

// ---------------------------------------------------------------------------
// input projections, BM=32 row-tile (unchanged from round 3):
//   - A (32 rows x 256 k) staged fp32->fp16 into 17 KB LDS, ONE barrier.
//   - A fragments (2 m-frags x 8 k-frags) held in 64 VGPRs.
//   - B streamed from L2 in fragment order (1 KB coalesced wave-loads);
//     2 MFMAs per B fragment.  NO loop barriers.
// blockIdx.y==0: value -> v_proj (fp16, N=256; 4 frags/wave)
// blockIdx.y==1: query -> off_b/attn_b (fp32, N=384; 6 frags/wave)
// ---------------------------------------------------------------------------
__global__ __launch_bounds__(256, 4)
void gemm_proj(const float* __restrict__ Aval, const float* __restrict__ Aqry,
               const f16_t* __restrict__ WtV, const f16_t* __restrict__ WtQ,
               const float* __restrict__ b_val, const float* __restrict__ b_off,
               const float* __restrict__ b_attn,
               f16_t* __restrict__ v_proj, float* __restrict__ off_b,
               float* __restrict__ attn_b, int M)
{
    __shared__ __align__(16) f16_t As[32][264];   // pad 8 f16 per row

    const int t  = threadIdx.x;
    const int m0 = blockIdx.x * 32;
    const bool isVal = (blockIdx.y == 0);
    const float* __restrict__ Af = isVal ? Aval : Aqry;
    const f16_t* __restrict__ Wt = isVal ? WtV : WtQ;
    const int JW = isVal ? 4 : 6;      // n-frags per wave

    // ---- stage A: 32 rows x 256 fp32 -> fp16 LDS (thread: 1 row x 32 cols)
    {
        const int r  = t >> 3;            // 0..31
        const int c0 = (t & 7) * 32;      // 0..224
        const int gm = m0 + r;
        #pragma unroll
        for (int u = 0; u < 2; ++u) {
            f16_t tmp[16];
            if (gm < M) {
                #pragma unroll
                for (int q = 0; q < 4; ++q) {
                    const float4 v4 = *(const float4*)(Af + (size_t)gm * 256 + c0 + u * 16 + q * 4);
                    tmp[q*4+0] = (f16_t)v4.x; tmp[q*4+1] = (f16_t)v4.y;
                    tmp[q*4+2] = (f16_t)v4.z; tmp[q*4+3] = (f16_t)v4.w;
                }
            } else {
                #pragma unroll
                for (int q = 0; q < 16; ++q) tmp[q] = (f16_t)0.f;
            }
            *(f16x8*)&As[r][c0 + u * 16]     = *(const f16x8*)&tmp[0];
            *(f16x8*)&As[r][c0 + u * 16 + 8] = *(const f16x8*)&tmp[8];
        }
    }
    __syncthreads();

    const int lane = t & 63;
    const int w    = t >> 6;
    const int quad = lane >> 4, l16 = lane & 15;

    // A fragments: 2 m-frags x full 256 k in registers (16 x f16x8 = 64 VGPRs)
    f16x8 af[2][8];
    #pragma unroll
    for (int mi = 0; mi < 2; ++mi)
        #pragma unroll
        for (int kf = 0; kf < 8; ++kf)
            af[mi][kf] = *(const f16x8*)&As[mi * 16 + l16][kf * 32 + quad * 8];

    // ---- MFMA loop: B fragment-order coalesced loads, no barriers
    for (int j = 0; j < JW; ++j) {
        const int nf = (isVal ? w * 4 : w * 6) + j;
        const f16_t* __restrict__ bp = Wt + (size_t)nf * 4096 + lane * 8;

        f32x4 acc0 = {0.f, 0.f, 0.f, 0.f};
        f32x4 acc1 = {0.f, 0.f, 0.f, 0.f};
        #pragma unroll
        for (int kf = 0; kf < 8; ++kf) {
            const f16x8 bfr = *(const f16x8*)(bp + kf * 512);
            acc0 = __builtin_amdgcn_mfma_f32_16x16x32_f16(af[0][kf], bfr, acc0, 0, 0, 0);
            acc1 = __builtin_amdgcn_mfma_f32_16x16x32_f16(af[1][kf], bfr, acc1, 0, 0, 0);
        }

        const int n  = nf * 16 + l16;     // global output col
        const float bv = isVal ? b_val[n] : (n < 256 ? b_off[n] : b_attn[n - 256]);
        #pragma unroll
        for (int r = 0; r < 4; ++r) {
            const int gm0 = m0 + quad * 4 + r;
            const int gm1 = gm0 + 16;
            if (isVal) {
                if (gm0 < M) v_proj[(size_t)gm0 * 256 + n] = (f16_t)(acc0[r] + bv);
                if (gm1 < M) v_proj[(size_t)gm1 * 256 + n] = (f16_t)(acc1[r] + bv);
            } else if (n < 256) {
                if (gm0 < M) off_b[(size_t)gm0 * 256 + n] = acc0[r] + bv;
                if (gm1 < M) off_b[(size_t)gm1 * 256 + n] = acc1[r] + bv;
            } else {
                if (gm0 < M) attn_b[(size_t)gm0 * 128 + (n - 256)] = acc0[r] + bv;
                if (gm1 < M) attn_b[(size_t)gm1 * 128 + (n - 256)] = acc1[r] + bv;
            }
        }
    }
}

// ---------------------------------------------------------------------------
// fused softmax + bilinear sampling + OUTPUT PROJECTION.
// 32 queries/block, 256 threads = ONE thread per (q,h) owning all 32
// channels -> coordinate/softmax/weight math computed ONCE per (q,h).
// exp2-form softmax.  u32-index saddr-form gathers.
// Sampled 32x256 tile -> LDS -> 2x(16x256) @ Wo^T via MFMA (frag-order B).
// amdgpu_waves_per_eu(4,4): pin occupancy target at 4 waves/EU so the
// allocator uses the full 128-VGPR budget instead of squeezing to 64 and
// spilling ~2 GB of scratch traffic (round-5 failure mode).
// ---------------------------------------------------------------------------
__global__ __launch_bounds__(256)
__attribute__((amdgpu_waves_per_eu(4, 4)))
void msda_fused(const f16_t* __restrict__ v,      // (B, S, 256) fp16
                const float* __restrict__ off,    // (B*Q, 256)
                const float* __restrict__ attn,   // (B*Q, 128) RAW logits
                const float* __restrict__ ref,    // (B*Q, L, 2)
                const f16_t* __restrict__ WoT,    // fragment-order f16
                const float* __restrict__ b_out,
                float* __restrict__ out,          // (B*Q, 256) fp32
                int BQ)
{
    constexpr int SH[4] = {100, 50, 25, 13};
    constexpr int SW[4] = {150, 75, 38, 19};
    constexpr int ST[4] = {0, 15000, 18750, 19700};
    constexpr float LOG2E = 1.4426950408889634f;

    __shared__ __align__(16) f16_t Samp[32][264];   // pad 8 -> row stride 528 B

    const int t   = threadIdx.x;
    const int bq0 = blockIdx.x * 32;

    // ---------------- sampling phase: 1 thread per (q,h) ----------------
    {
        const int qi = t >> 3;          // 0..31
        const int h  = t & 7;
        const int bq = bq0 + qi;

        float acc[32];
        #pragma unroll
        for (int c = 0; c < 32; ++c) acc[c] = 0.f;

        if (bq < BQ) {
            const f16x8* __restrict__ vp = (const f16x8*)v;
            // u32 index in f16x8 units; saddr-form loads (no 64-bit carry math)
            const unsigned hoff = (unsigned)(h * 4)
                                + (bq >= Q_ ? (unsigned)(Q_ * (E_ / 8)) : 0u);

            const float* __restrict__ offp  = off  + (size_t)bq * 256 + h * 32;
            const float* __restrict__ attnp = attn + (size_t)bq * 128 + h * 16;

            // softmax over 16 raw logits (exp2 form: 1 fma + 1 v_exp each)
            float aw[16];
            #pragma unroll
            for (int i = 0; i < 4; ++i) {
                const float4 x = *(const float4*)(attnp + i * 4);
                aw[i*4+0] = x.x; aw[i*4+1] = x.y; aw[i*4+2] = x.z; aw[i*4+3] = x.w;
            }
            float mx = aw[0];
            #pragma unroll
            for (int i = 1; i < 16; ++i) mx = fmaxf(mx, aw[i]);
            const float mb = mx * LOG2E;
            float sum = 0.f;
            #pragma unroll
            for (int i = 0; i < 16; ++i) {
                aw[i] = exp2f(fmaf(aw[i], LOG2E, -mb));
                sum += aw[i];
            }
            const float inv = 1.f / sum;
            #pragma unroll
            for (int i = 0; i < 16; ++i) aw[i] *= inv;

            const float4 r01 = *(const float4*)(ref + (size_t)bq * 8);
            const float4 r23 = *(const float4*)(ref + (size_t)bq * 8 + 4);
            const float rx[4] = {r01.x, r01.z, r23.x, r23.z};
            const float ry[4] = {r01.y, r01.w, r23.y, r23.w};

            #pragma unroll
            for (int l = 0; l < L_; ++l) {
                const float fW = (float)SW[l], fH = (float)SH[l];
                const int   Ww = SW[l], Hh = SH[l], st = ST[l];
                #pragma unroll
                for (int pp = 0; pp < 2; ++pp) {
                    const float4 o2 = *(const float4*)(offp + l * 8 + pp * 4);
                    #pragma unroll
                    for (int q = 0; q < 2; ++q) {
                        const int   p  = pp * 2 + q;
                        const float ox = q ? o2.z : o2.x;
                        const float oy = q ? o2.w : o2.y;
                        const float wA = aw[l * 4 + p];
                        const float gx = fmaf(rx[l], fW, ox) - 0.5f;
                        const float gy = fmaf(ry[l], fH, oy) - 0.5f;
                        const float x0f = floorf(gx), y0f = floorf(gy);
                        const int   x0  = (int)x0f,   y0  = (int)y0f;
                        const float wx1 = gx - x0f,   wy1 = gy - y0f;
                        const float wx0 = 1.f - wx1,  wy0 = 1.f - wy1;

                        const float mxw0 = ((unsigned)x0     < (unsigned)Ww) ? wx0 : 0.f;
                        const float mxw1 = ((unsigned)(x0+1) < (unsigned)Ww) ? wx1 : 0.f;
                        const float myw0 = ((unsigned)y0     < (unsigned)Hh) ? wy0 : 0.f;
                        const float myw1 = ((unsigned)(y0+1) < (unsigned)Hh) ? wy1 : 0.f;
                        const int xc0 = min(max(x0, 0),     Ww - 1);
                        const int xc1 = min(max(x0 + 1, 0), Ww - 1);
                        const int yc0 = min(max(y0, 0),     Hh - 1);
                        const int yc1 = min(max(y0 + 1, 0), Hh - 1);

                        const float w00 = wA * mxw0 * myw0;
                        const float w10 = wA * mxw1 * myw0;
                        const float w01 = wA * mxw0 * myw1;
                        const float w11 = wA * mxw1 * myw1;

                        const unsigned r0 = (unsigned)(st + yc0 * Ww);
                        const unsigned r1 = (unsigned)(st + yc1 * Ww);
                        const unsigned i00 = (r0 + (unsigned)xc0) * 32u + hoff;
                        const unsigned i10 = (r0 + (unsigned)xc1) * 32u + hoff;
                        const unsigned i01 = (r1 + (unsigned)xc0) * 32u + hoff;
                        const unsigned i11 = (r1 + (unsigned)xc1) * 32u + hoff;

                        #pragma unroll
                        for (int u = 0; u < 4; ++u) {
                            const f16x8 s00 = vp[i00 + (unsigned)u];
                            const f16x8 s10 = vp[i10 + (unsigned)u];
                            const f16x8 s01 = vp[i01 + (unsigned)u];
                            const f16x8 s11 = vp[i11 + (unsigned)u];
                            #pragma unroll
                            for (int c = 0; c < 8; ++c) {
                                acc[u*8+c] = fmaf(w00, (float)s00[c], acc[u*8+c]);
                                acc[u*8+c] = fmaf(w10, (float)s10[c], acc[u*8+c]);
                                acc[u*8+c] = fmaf(w01, (float)s01[c], acc[u*8+c]);
                                acc[u*8+c] = fmaf(w11, (float)s11[c], acc[u*8+c]);
                            }
                        }
                    }
                }
            }
        }

        #pragma unroll
        for (int u = 0; u < 4; ++u) {
            f16x8 o;
            #pragma unroll
            for (int c = 0; c < 8; ++c) o[c] = (f16_t)acc[u*8+c];
            *(f16x8*)&Samp[qi][h * 32 + u * 8] = o;
        }
    }

    __syncthreads();

    // ------- output projection: 2 x (16x256) @ WoT^T (frag-order B) -------
    const int lane = t & 63;
    const int w    = t >> 6;              // wave -> n-range w*64..+63
    const int quad = lane >> 4, l16 = lane & 15;

    #pragma unroll
    for (int mi = 0; mi < 2; ++mi) {
        f16x8 af[8];
        #pragma unroll
        for (int kf = 0; kf < 8; ++kf)
            af[kf] = *(const f16x8*)&Samp[mi * 16 + l16][kf * 32 + quad * 8];

        #pragma unroll
        for (int j = 0; j < 4; ++j) {
            const int nf = w * 4 + j;
            const f16_t* bp = WoT + (size_t)nf * 4096 + lane * 8;
            f32x4 a4 = {0.f, 0.f, 0.f, 0.f};
            #pragma unroll
            for (int kf = 0; kf < 8; ++kf) {
                const f16x8 bfr = *(const f16x8*)(bp + kf * 512);
                a4 = __builtin_amdgcn_mfma_f32_16x16x32_f16(af[kf], bfr, a4, 0, 0, 0);
            }
            const int n  = nf * 16 + l16;
            const float bv = b_out[n];
            #pragma unroll
            for (int r = 0; r < 4; ++r) {
                const int gm = bq0 + mi * 16 + quad * 4 + r;
                if (gm < BQ)
                    out[(size_t)gm * 256 + n] = a4[r] + bv;
            }
        }
    }
}

// ---------------------------------------------------------------------------
extern "C" void kernel_launch(void* const* d_in, const int* in_sizes, int n_in,
                              void* d_out, int out_size, void* d_ws, size_t ws_size,
                              hipStream_t stream)
{
    const float* query  = (const float*)d_in[0];
    const float* value  = (const float*)d_in[1];
    const float* refpts = (const float*)d_in[2];
    const float* w_off  = (const float*)d_in[4];
    const float* b_off  = (const float*)d_in[5];
    const float* w_attn = (const float*)d_in[6];
    const float* b_attn = (const float*)d_in[7];
    const float* w_val  = (const float*)d_in[8];
    const float* b_val  = (const float*)d_in[9];
    const float* w_out  = (const float*)d_in[10];
    const float* b_out  = (const float*)d_in[11];
    float* out = (float*)d_out;

    const int BQ = B_ * Q_;            // 39894

    // workspace layout
    char* ws = (char*)d_ws;
    f16_t* v_proj = (f16_t*)ws;                       ws += (size_t)BQ * 256 * 2;
    float* off_b  = (float*)ws;                       ws += (size_t)BQ * 256 * 4;
    float* attn_b = (float*)ws;                       ws += (size_t)BQ * 128 * 4;
    f16_t* WtV    = (f16_t*)ws;                       ws += (size_t)256 * 256 * 2;
    f16_t* WtQ    = (f16_t*)ws;                       ws += (size_t)384 * 256 * 2;
    f16_t* WtO    = (f16_t*)ws;

    const dim3 blk(256);

    // 0) all weight transposes -> fragment-order fp16, one dispatch
    transpose_all<<<dim3(8, 8, 4), blk, 0, stream>>>(w_val, w_off, w_attn, w_out,
                                                     WtV, WtQ, WtO);

    const int mg32 = (BQ + 31) / 32;   // 1247

    // 1) input projections: BM=32, A read once, coalesced frag-order B
    gemm_proj<<<dim3(mg32, 2), blk, 0, stream>>>(
        value, query, WtV, WtQ, b_val, b_off, b_attn,
        v_proj, off_b, attn_b, BQ);

    // 2) fused softmax + sampling + output projection -> d_out
    msda_fused<<<dim3(mg32), blk, 0, stream>>>(
        v_proj, off_b, attn_b, refpts, WtO, b_out, out, BQ);
}

// Round 8
// 311.105 us; speedup vs baseline: 2.4000x; 2.4000x over previous
//
#include <hip/hip_runtime.h>
#include <math.h>

// ---------------- problem constants (fixed by setup_inputs) ----------------
#define B_    2
#define Q_    19947
#define E_    256
#define H_    8
#define D_    32
#define L_    4
#define P_    4

typedef _Float16 f16_t;
typedef f16_t f16x8 __attribute__((ext_vector_type(8)));
typedef f16_t f16x4 __attribute__((ext_vector_type(4)));
typedef float f32x4 __attribute__((ext_vector_type(4)));

// ---------------------------------------------------------------------------
// Weight transpose + fp16 convert + MFMA-fragment-order swizzle.
// Input  fp32 [K=256][N].  Output f16 in fragment order:
//   n -> (nf = n>>4, l16 = n&15),  k -> (kf = k>>5, quad = (k>>3)&3, e = k&7)
//   elem index = (nf*8 + kf)*512 + (quad*16 + l16)*8 + e
// z: 0=w_val->WtV(256) 1=w_off->WtQ(256) 2=w_attn->WtQ+64K(128) 3=w_out->WtO(256)
// ---------------------------------------------------------------------------
__global__ __launch_bounds__(256)
void transpose_all(const float* __restrict__ w_val, const float* __restrict__ w_off,
                   const float* __restrict__ w_attn, const float* __restrict__ w_out,
                   f16_t* __restrict__ WtV, f16_t* __restrict__ WtQ,
                   f16_t* __restrict__ WtO)
{
    const float* in; f16_t* out; int N;
    switch (blockIdx.z) {
        case 0:  in = w_val;  out = WtV;             N = 256; break;
        case 1:  in = w_off;  out = WtQ;             N = 256; break;
        case 2:  in = w_attn; out = WtQ + 256 * 256; N = 128; break;
        default: in = w_out;  out = WtO;             N = 256; break;
    }
    const int nt = blockIdx.x * 32;
    if (nt >= N) return;
    const int kt = blockIdx.y * 32;          // k-tile (multiple of 32 -> kf fixed)

    __shared__ float tile[32][33];
    const int x  = threadIdx.x & 31;
    const int y0 = threadIdx.x >> 5;          // 0..7
    #pragma unroll
    for (int p = 0; p < 4; ++p)
        tile[y0 + p * 8][x] = in[(size_t)(kt + y0 + p * 8) * N + nt + x];
    __syncthreads();
    const int kf = kt >> 5;
    #pragma unroll
    for (int p = 0; p < 4; ++p) {
        const int n    = nt + y0 + p * 8;
        const int nf   = n >> 4, l16 = n & 15;
        const int quad = (x >> 3) & 3, e = x & 7;
        out[(size_t)(nf * 8 + kf) * 512 + (quad * 16 + l16) * 8 + e]
            = (f16_t)tile[x][y0 + p * 8];
    }
}

// ---------------------------------------------------------------------------
// input projections, BM=32 row-tile (round-3 proven), ONE change:
// value-projection output layout is now (b, h, s, d):
//   v_proj[((b*8+h)*Q_ + s)*32 + d]
// so x-adjacent bilinear corners in msda land 64 B apart (same 128-B line).
// ---------------------------------------------------------------------------
__global__ __launch_bounds__(256, 4)
void gemm_proj(const float* __restrict__ Aval, const float* __restrict__ Aqry,
               const f16_t* __restrict__ WtV, const f16_t* __restrict__ WtQ,
               const float* __restrict__ b_val, const float* __restrict__ b_off,
               const float* __restrict__ b_attn,
               f16_t* __restrict__ v_proj, float* __restrict__ off_b,
               float* __restrict__ attn_b, int M)
{
    __shared__ __align__(16) f16_t As[32][264];   // pad 8 f16 per row

    const int t  = threadIdx.x;
    const int m0 = blockIdx.x * 32;
    const bool isVal = (blockIdx.y == 0);
    const float* __restrict__ Af = isVal ? Aval : Aqry;
    const f16_t* __restrict__ Wt = isVal ? WtV : WtQ;
    const int JW = isVal ? 4 : 6;      // n-frags per wave

    // ---- stage A: 32 rows x 256 fp32 -> fp16 LDS (thread: 1 row x 32 cols)
    {
        const int r  = t >> 3;            // 0..31
        const int c0 = (t & 7) * 32;      // 0..224
        const int gm = m0 + r;
        #pragma unroll
        for (int u = 0; u < 2; ++u) {
            f16_t tmp[16];
            if (gm < M) {
                #pragma unroll
                for (int q = 0; q < 4; ++q) {
                    const float4 v4 = *(const float4*)(Af + (size_t)gm * 256 + c0 + u * 16 + q * 4);
                    tmp[q*4+0] = (f16_t)v4.x; tmp[q*4+1] = (f16_t)v4.y;
                    tmp[q*4+2] = (f16_t)v4.z; tmp[q*4+3] = (f16_t)v4.w;
                }
            } else {
                #pragma unroll
                for (int q = 0; q < 16; ++q) tmp[q] = (f16_t)0.f;
            }
            *(f16x8*)&As[r][c0 + u * 16]     = *(const f16x8*)&tmp[0];
            *(f16x8*)&As[r][c0 + u * 16 + 8] = *(const f16x8*)&tmp[8];
        }
    }
    __syncthreads();

    const int lane = t & 63;
    const int w    = t >> 6;
    const int quad = lane >> 4, l16 = lane & 15;

    // A fragments: 2 m-frags x full 256 k in registers (16 x f16x8 = 64 VGPRs)
    f16x8 af[2][8];
    #pragma unroll
    for (int mi = 0; mi < 2; ++mi)
        #pragma unroll
        for (int kf = 0; kf < 8; ++kf)
            af[mi][kf] = *(const f16x8*)&As[mi * 16 + l16][kf * 32 + quad * 8];

    // ---- MFMA loop: B fragment-order coalesced loads, no barriers
    for (int j = 0; j < JW; ++j) {
        const int nf = (isVal ? w * 4 : w * 6) + j;
        const f16_t* __restrict__ bp = Wt + (size_t)nf * 4096 + lane * 8;

        f32x4 acc0 = {0.f, 0.f, 0.f, 0.f};
        f32x4 acc1 = {0.f, 0.f, 0.f, 0.f};
        #pragma unroll
        for (int kf = 0; kf < 8; ++kf) {
            const f16x8 bfr = *(const f16x8*)(bp + kf * 512);
            acc0 = __builtin_amdgcn_mfma_f32_16x16x32_f16(af[0][kf], bfr, acc0, 0, 0, 0);
            acc1 = __builtin_amdgcn_mfma_f32_16x16x32_f16(af[1][kf], bfr, acc1, 0, 0, 0);
        }

        const int n  = nf * 16 + l16;     // global output col
        const float bv = isVal ? b_val[n] : (n < 256 ? b_off[n] : b_attn[n - 256]);
        #pragma unroll
        for (int r = 0; r < 4; ++r) {
            const int gm0 = m0 + quad * 4 + r;
            const int gm1 = gm0 + 16;
            if (isVal) {
                const int h = n >> 5, d = n & 31;
                if (gm0 < M) {
                    const int b0 = gm0 / Q_, s0 = gm0 - b0 * Q_;
                    v_proj[((size_t)(b0 * 8 + h) * Q_ + s0) * 32 + d] = (f16_t)(acc0[r] + bv);
                }
                if (gm1 < M) {
                    const int b1 = gm1 / Q_, s1 = gm1 - b1 * Q_;
                    v_proj[((size_t)(b1 * 8 + h) * Q_ + s1) * 32 + d] = (f16_t)(acc1[r] + bv);
                }
            } else if (n < 256) {
                if (gm0 < M) off_b[(size_t)gm0 * 256 + n] = acc0[r] + bv;
                if (gm1 < M) off_b[(size_t)gm1 * 256 + n] = acc1[r] + bv;
            } else {
                if (gm0 < M) attn_b[(size_t)gm0 * 128 + (n - 256)] = acc0[r] + bv;
                if (gm1 < M) attn_b[(size_t)gm1 * 128 + (n - 256)] = acc1[r] + bv;
            }
        }
    }
}

// ---------------------------------------------------------------------------
// fused softmax + bilinear sampling + OUTPUT PROJECTION (round-3 structure:
// 16 queries/block, 2 rounds of 8q x 8h x 4 lanes, acc[8], 60 VGPR, no spill).
// Changes vs round 3: exp2-form softmax; gathers use (b,h,s,d) v_proj layout
// via u32-index saddr loads (x-adjacent corners share a 128-B line).
// ---------------------------------------------------------------------------
__global__ __launch_bounds__(256, 4)
void msda_fused(const f16_t* __restrict__ v,      // (B, H, S, 32) fp16
                const float* __restrict__ off,    // (B*Q, 256)
                const float* __restrict__ attn,   // (B*Q, 128) RAW logits
                const float* __restrict__ ref,    // (B*Q, L, 2)
                const f16_t* __restrict__ WoT,    // fragment-order f16
                const float* __restrict__ b_out,
                float* __restrict__ out,          // (B*Q, 256) fp32
                int BQ)
{
    constexpr int SH[4] = {100, 50, 25, 13};
    constexpr int SW[4] = {150, 75, 38, 19};
    constexpr int ST[4] = {0, 15000, 18750, 19700};
    constexpr float LOG2E = 1.4426950408889634f;

    __shared__ __align__(16) f16_t Samp[16][264];   // pad 8 -> row stride 528 B

    const int t   = threadIdx.x;
    const int bq0 = blockIdx.x * 16;

    // ---------------- sampling phase: 2 rounds of 8 queries ----------------
    #pragma unroll
    for (int r = 0; r < 2; ++r) {
        const int g    = t >> 2;                 // 0..63
        const int qi   = (g >> 3) + r * 8;       // 0..15
        const int h    = g & 7;
        const int lane = t & 3;
        const int bq   = bq0 + qi;

        float acc[8] = {0.f, 0.f, 0.f, 0.f, 0.f, 0.f, 0.f, 0.f};

        if (bq < BQ) {
            const f16x8* __restrict__ vp = (const f16x8*)v;
            // u32 base index in f16x8 units: ((b*8+h)*Q_)*4 + lane
            const unsigned vb = (unsigned)(((bq >= Q_ ? 8 : 0) + h) * (unsigned)Q_) * 4u
                              + (unsigned)lane;
            const float* __restrict__ offp  = off  + (size_t)bq * 256 + h * 32;
            const float* __restrict__ attnp = attn + (size_t)bq * 128 + h * 16;

            // softmax over 16 raw logits (exp2 form)
            float aw[16];
            #pragma unroll
            for (int i = 0; i < 4; ++i) {
                const float4 x = *(const float4*)(attnp + i * 4);
                aw[i*4+0] = x.x; aw[i*4+1] = x.y; aw[i*4+2] = x.z; aw[i*4+3] = x.w;
            }
            float mx = aw[0];
            #pragma unroll
            for (int i = 1; i < 16; ++i) mx = fmaxf(mx, aw[i]);
            const float mb = mx * LOG2E;
            float sum = 0.f;
            #pragma unroll
            for (int i = 0; i < 16; ++i) {
                aw[i] = exp2f(fmaf(aw[i], LOG2E, -mb));
                sum += aw[i];
            }
            const float inv = 1.f / sum;
            #pragma unroll
            for (int i = 0; i < 16; ++i) aw[i] *= inv;

            const float4 r01 = *(const float4*)(ref + (size_t)bq * 8);
            const float4 r23 = *(const float4*)(ref + (size_t)bq * 8 + 4);
            const float rx[4] = {r01.x, r01.z, r23.x, r23.z};
            const float ry[4] = {r01.y, r01.w, r23.y, r23.w};

            #pragma unroll
            for (int l = 0; l < L_; ++l) {
                const float fW = (float)SW[l], fH = (float)SH[l];
                const int   Ww = SW[l], Hh = SH[l], st = ST[l];
                #pragma unroll
                for (int pp = 0; pp < 2; ++pp) {
                    const float4 o2 = *(const float4*)(offp + l * 8 + pp * 4);
                    #pragma unroll
                    for (int q = 0; q < 2; ++q) {
                        const int   p  = pp * 2 + q;
                        const float ox = q ? o2.z : o2.x;
                        const float oy = q ? o2.w : o2.y;
                        const float wA = aw[l * 4 + p];
                        const float gx = fmaf(rx[l], fW, ox) - 0.5f;
                        const float gy = fmaf(ry[l], fH, oy) - 0.5f;
                        const float x0f = floorf(gx), y0f = floorf(gy);
                        const int   x0  = (int)x0f,   y0  = (int)y0f;
                        const float wx1 = gx - x0f,   wy1 = gy - y0f;
                        const float wx0 = 1.f - wx1,  wy0 = 1.f - wy1;

                        const float mxw0 = ((unsigned)x0     < (unsigned)Ww) ? wx0 : 0.f;
                        const float mxw1 = ((unsigned)(x0+1) < (unsigned)Ww) ? wx1 : 0.f;
                        const float myw0 = ((unsigned)y0     < (unsigned)Hh) ? wy0 : 0.f;
                        const float myw1 = ((unsigned)(y0+1) < (unsigned)Hh) ? wy1 : 0.f;
                        const int xc0 = min(max(x0, 0),     Ww - 1);
                        const int xc1 = min(max(x0 + 1, 0), Ww - 1);
                        const int yc0 = min(max(y0, 0),     Hh - 1);
                        const int yc1 = min(max(y0 + 1, 0), Hh - 1);

                        const float w00 = wA * mxw0 * myw0;
                        const float w10 = wA * mxw1 * myw0;
                        const float w01 = wA * mxw0 * myw1;
                        const float w11 = wA * mxw1 * myw1;

                        const unsigned r0 = (unsigned)(st + yc0 * Ww);
                        const unsigned r1 = (unsigned)(st + yc1 * Ww);
                        const f16x8 s00 = vp[vb + (r0 + (unsigned)xc0) * 4u];
                        const f16x8 s10 = vp[vb + (r0 + (unsigned)xc1) * 4u];
                        const f16x8 s01 = vp[vb + (r1 + (unsigned)xc0) * 4u];
                        const f16x8 s11 = vp[vb + (r1 + (unsigned)xc1) * 4u];

                        #pragma unroll
                        for (int c = 0; c < 8; ++c) {
                            acc[c] = fmaf(w00, (float)s00[c], acc[c]);
                            acc[c] = fmaf(w10, (float)s10[c], acc[c]);
                            acc[c] = fmaf(w01, (float)s01[c], acc[c]);
                            acc[c] = fmaf(w11, (float)s11[c], acc[c]);
                        }
                    }
                }
            }
        }

        f16x8 o;
        #pragma unroll
        for (int c = 0; c < 8; ++c) o[c] = (f16_t)acc[c];
        *(f16x8*)&Samp[qi][h * 32 + lane * 8] = o;
    }

    __syncthreads();

    // ---------------- output projection: 16x256 @ WoT^T (frag-order B) ----
    const int lane = t & 63;
    const int w    = t >> 6;              // wave -> n-range w*64..+63
    const int quad = lane >> 4, l16 = lane & 15;

    f16x8 af[8];
    #pragma unroll
    for (int kf = 0; kf < 8; ++kf)
        af[kf] = *(const f16x8*)&Samp[l16][kf * 32 + quad * 8];

    f32x4 acc4[4];
    #pragma unroll
    for (int j = 0; j < 4; ++j) {
        f32x4 z = {0.f, 0.f, 0.f, 0.f};
        acc4[j] = z;
    }

    #pragma unroll
    for (int j = 0; j < 4; ++j) {
        const int nf = w * 4 + j;
        const f16_t* bp = WoT + (size_t)nf * 4096 + lane * 8;
        #pragma unroll
        for (int kf = 0; kf < 8; ++kf) {
            const f16x8 bfr = *(const f16x8*)(bp + kf * 512);
            acc4[j] = __builtin_amdgcn_mfma_f32_16x16x32_f16(af[kf], bfr, acc4[j], 0, 0, 0);
        }
    }

    #pragma unroll
    for (int j = 0; j < 4; ++j) {
        const int n  = w * 64 + j * 16 + l16;
        const float bv = b_out[n];
        #pragma unroll
        for (int r = 0; r < 4; ++r) {
            const int gm = bq0 + quad * 4 + r;
            if (gm < BQ)
                out[(size_t)gm * 256 + n] = acc4[j][r] + bv;
        }
    }
}

// ---------------------------------------------------------------------------
extern "C" void kernel_launch(void* const* d_in, const int* in_sizes, int n_in,
                              void* d_out, int out_size, void* d_ws, size_t ws_size,
                              hipStream_t stream)
{
    const float* query  = (const float*)d_in[0];
    const float* value  = (const float*)d_in[1];
    const float* refpts = (const float*)d_in[2];
    const float* w_off  = (const float*)d_in[4];
    const float* b_off  = (const float*)d_in[5];
    const float* w_attn = (const float*)d_in[6];
    const float* b_attn = (const float*)d_in[7];
    const float* w_val  = (const float*)d_in[8];
    const float* b_val  = (const float*)d_in[9];
    const float* w_out  = (const float*)d_in[10];
    const float* b_out  = (const float*)d_in[11];
    float* out = (float*)d_out;

    const int BQ = B_ * Q_;            // 39894

    // workspace layout
    char* ws = (char*)d_ws;
    f16_t* v_proj = (f16_t*)ws;                       ws += (size_t)BQ * 256 * 2;
    float* off_b  = (float*)ws;                       ws += (size_t)BQ * 256 * 4;
    float* attn_b = (float*)ws;                       ws += (size_t)BQ * 128 * 4;
    f16_t* WtV    = (f16_t*)ws;                       ws += (size_t)256 * 256 * 2;
    f16_t* WtQ    = (f16_t*)ws;                       ws += (size_t)384 * 256 * 2;
    f16_t* WtO    = (f16_t*)ws;

    const dim3 blk(256);

    // 0) all weight transposes -> fragment-order fp16, one dispatch
    transpose_all<<<dim3(8, 8, 4), blk, 0, stream>>>(w_val, w_off, w_attn, w_out,
                                                     WtV, WtQ, WtO);

    const int mg32 = (BQ + 31) / 32;   // 1247

    // 1) input projections: BM=32, A read once, coalesced frag-order B
    gemm_proj<<<dim3(mg32, 2), blk, 0, stream>>>(
        value, query, WtV, WtQ, b_val, b_off, b_attn,
        v_proj, off_b, attn_b, BQ);

    // 2) fused softmax + sampling + output projection -> d_out
    const int mg16 = (BQ + 15) / 16;   // 2494
    msda_fused<<<dim3(mg16), blk, 0, stream>>>(
        v_proj, off_b, attn_b, refpts, WtO, b_out, out, BQ);
}

// Round 9
// 280.808 us; speedup vs baseline: 2.6589x; 1.1079x over previous
//
#include <hip/hip_runtime.h>
#include <math.h>

// ---------------- problem constants (fixed by setup_inputs) ----------------
#define B_    2
#define Q_    19947
#define E_    256
#define H_    8
#define D_    32
#define L_    4
#define P_    4

typedef _Float16 f16_t;
typedef f16_t f16x8 __attribute__((ext_vector_type(8)));
typedef f16_t f16x4 __attribute__((ext_vector_type(4)));
typedef float f32x4 __attribute__((ext_vector_type(4)));

// ---------------------------------------------------------------------------
// Weight transpose + fp16 convert + MFMA-fragment-order swizzle.
// Input  fp32 [K=256][N].  Output f16 in fragment order:
//   n -> (nf = n>>4, l16 = n&15),  k -> (kf = k>>5, quad = (k>>3)&3, e = k&7)
//   elem index = (nf*8 + kf)*512 + (quad*16 + l16)*8 + e
// z: 0=w_val->WtV(256) 1=w_off->WtQ(256) 2=w_attn->WtQ+64K(128) 3=w_out->WtO(256)
// ---------------------------------------------------------------------------
__global__ __launch_bounds__(256)
void transpose_all(const float* __restrict__ w_val, const float* __restrict__ w_off,
                   const float* __restrict__ w_attn, const float* __restrict__ w_out,
                   f16_t* __restrict__ WtV, f16_t* __restrict__ WtQ,
                   f16_t* __restrict__ WtO)
{
    const float* in; f16_t* out; int N;
    switch (blockIdx.z) {
        case 0:  in = w_val;  out = WtV;             N = 256; break;
        case 1:  in = w_off;  out = WtQ;             N = 256; break;
        case 2:  in = w_attn; out = WtQ + 256 * 256; N = 128; break;
        default: in = w_out;  out = WtO;             N = 256; break;
    }
    const int nt = blockIdx.x * 32;
    if (nt >= N) return;
    const int kt = blockIdx.y * 32;          // k-tile (multiple of 32 -> kf fixed)

    __shared__ float tile[32][33];
    const int x  = threadIdx.x & 31;
    const int y0 = threadIdx.x >> 5;          // 0..7
    #pragma unroll
    for (int p = 0; p < 4; ++p)
        tile[y0 + p * 8][x] = in[(size_t)(kt + y0 + p * 8) * N + nt + x];
    __syncthreads();
    const int kf = kt >> 5;
    #pragma unroll
    for (int p = 0; p < 4; ++p) {
        const int n    = nt + y0 + p * 8;
        const int nf   = n >> 4, l16 = n & 15;
        const int quad = (x >> 3) & 3, e = x & 7;
        out[(size_t)(nf * 8 + kf) * 512 + (quad * 16 + l16) * 8 + e]
            = (f16_t)tile[x][y0 + p * 8];
    }
}

// ---------------------------------------------------------------------------
// input projections, BM=32 row-tile (round-3 proven, byte-identical):
//   - A (32 rows x 256 k) staged fp32->fp16 into 17 KB LDS, ONE barrier.
//   - A fragments (2 m-frags x 8 k-frags) held in 64 VGPRs.
//   - B streamed from L2 in fragment order (1 KB coalesced wave-loads);
//     2 MFMAs per B fragment.  NO loop barriers.
// v_proj layout: (s, h*32+d) — row 512 B keeps all 8 heads of a sample in
// 4 cache lines; heads sample near-identical pixels (offsets ~ +-0.3 px),
// so this layout maximizes inter-head line reuse (r8 falsified (b,h,s,d)).
// ---------------------------------------------------------------------------
__global__ __launch_bounds__(256, 4)
void gemm_proj(const float* __restrict__ Aval, const float* __restrict__ Aqry,
               const f16_t* __restrict__ WtV, const f16_t* __restrict__ WtQ,
               const float* __restrict__ b_val, const float* __restrict__ b_off,
               const float* __restrict__ b_attn,
               f16_t* __restrict__ v_proj, float* __restrict__ off_b,
               float* __restrict__ attn_b, int M)
{
    __shared__ __align__(16) f16_t As[32][264];   // pad 8 f16 per row

    const int t  = threadIdx.x;
    const int m0 = blockIdx.x * 32;
    const bool isVal = (blockIdx.y == 0);
    const float* __restrict__ Af = isVal ? Aval : Aqry;
    const f16_t* __restrict__ Wt = isVal ? WtV : WtQ;
    const int JW = isVal ? 4 : 6;      // n-frags per wave

    // ---- stage A: 32 rows x 256 fp32 -> fp16 LDS (thread: 1 row x 32 cols)
    {
        const int r  = t >> 3;            // 0..31
        const int c0 = (t & 7) * 32;      // 0..224
        const int gm = m0 + r;
        #pragma unroll
        for (int u = 0; u < 2; ++u) {
            f16_t tmp[16];
            if (gm < M) {
                #pragma unroll
                for (int q = 0; q < 4; ++q) {
                    const float4 v4 = *(const float4*)(Af + (size_t)gm * 256 + c0 + u * 16 + q * 4);
                    tmp[q*4+0] = (f16_t)v4.x; tmp[q*4+1] = (f16_t)v4.y;
                    tmp[q*4+2] = (f16_t)v4.z; tmp[q*4+3] = (f16_t)v4.w;
                }
            } else {
                #pragma unroll
                for (int q = 0; q < 16; ++q) tmp[q] = (f16_t)0.f;
            }
            *(f16x8*)&As[r][c0 + u * 16]     = *(const f16x8*)&tmp[0];
            *(f16x8*)&As[r][c0 + u * 16 + 8] = *(const f16x8*)&tmp[8];
        }
    }
    __syncthreads();

    const int lane = t & 63;
    const int w    = t >> 6;
    const int quad = lane >> 4, l16 = lane & 15;

    // A fragments: 2 m-frags x full 256 k in registers (16 x f16x8 = 64 VGPRs)
    f16x8 af[2][8];
    #pragma unroll
    for (int mi = 0; mi < 2; ++mi)
        #pragma unroll
        for (int kf = 0; kf < 8; ++kf)
            af[mi][kf] = *(const f16x8*)&As[mi * 16 + l16][kf * 32 + quad * 8];

    // ---- MFMA loop: B fragment-order coalesced loads, no barriers
    for (int j = 0; j < JW; ++j) {
        const int nf = (isVal ? w * 4 : w * 6) + j;
        const f16_t* __restrict__ bp = Wt + (size_t)nf * 4096 + lane * 8;

        f32x4 acc0 = {0.f, 0.f, 0.f, 0.f};
        f32x4 acc1 = {0.f, 0.f, 0.f, 0.f};
        #pragma unroll
        for (int kf = 0; kf < 8; ++kf) {
            const f16x8 bfr = *(const f16x8*)(bp + kf * 512);
            acc0 = __builtin_amdgcn_mfma_f32_16x16x32_f16(af[0][kf], bfr, acc0, 0, 0, 0);
            acc1 = __builtin_amdgcn_mfma_f32_16x16x32_f16(af[1][kf], bfr, acc1, 0, 0, 0);
        }

        const int n  = nf * 16 + l16;     // global output col
        const float bv = isVal ? b_val[n] : (n < 256 ? b_off[n] : b_attn[n - 256]);
        #pragma unroll
        for (int r = 0; r < 4; ++r) {
            const int gm0 = m0 + quad * 4 + r;
            const int gm1 = gm0 + 16;
            if (isVal) {
                if (gm0 < M) v_proj[(size_t)gm0 * 256 + n] = (f16_t)(acc0[r] + bv);
                if (gm1 < M) v_proj[(size_t)gm1 * 256 + n] = (f16_t)(acc1[r] + bv);
            } else if (n < 256) {
                if (gm0 < M) off_b[(size_t)gm0 * 256 + n] = acc0[r] + bv;
                if (gm1 < M) off_b[(size_t)gm1 * 256 + n] = acc1[r] + bv;
            } else {
                if (gm0 < M) attn_b[(size_t)gm0 * 128 + (n - 256)] = acc0[r] + bv;
                if (gm1 < M) attn_b[(size_t)gm1 * 128 + (n - 256)] = acc1[r] + bv;
            }
        }
    }
}

// ---------------------------------------------------------------------------
// fused softmax + bilinear sampling + OUTPUT PROJECTION (round-3 structure:
// 16 queries/block, 2 rounds of 8q x 8h x 4 lanes, acc[8], no spill).
// vs round 3: exp2-form softmax; u32-index saddr gathers (same (s,e) layout,
// kills 64-bit per-corner address chains); s_setprio around the MFMA tail.
// ---------------------------------------------------------------------------
__global__ __launch_bounds__(256, 4)
void msda_fused(const f16_t* __restrict__ v,      // (B, S, 256) fp16
                const float* __restrict__ off,    // (B*Q, 256)
                const float* __restrict__ attn,   // (B*Q, 128) RAW logits
                const float* __restrict__ ref,    // (B*Q, L, 2)
                const f16_t* __restrict__ WoT,    // fragment-order f16
                const float* __restrict__ b_out,
                float* __restrict__ out,          // (B*Q, 256) fp32
                int BQ)
{
    constexpr int SH[4] = {100, 50, 25, 13};
    constexpr int SW[4] = {150, 75, 38, 19};
    constexpr int ST[4] = {0, 15000, 18750, 19700};
    constexpr float LOG2E = 1.4426950408889634f;

    __shared__ __align__(16) f16_t Samp[16][264];   // pad 8 -> row stride 528 B

    const int t   = threadIdx.x;
    const int bq0 = blockIdx.x * 16;

    // ---------------- sampling phase: 2 rounds of 8 queries ----------------
    #pragma unroll
    for (int r = 0; r < 2; ++r) {
        const int g    = t >> 2;                 // 0..63
        const int qi   = (g >> 3) + r * 8;       // 0..15
        const int h    = g & 7;
        const int lane = t & 3;
        const int bq   = bq0 + qi;

        float acc[8] = {0.f, 0.f, 0.f, 0.f, 0.f, 0.f, 0.f, 0.f};

        if (bq < BQ) {
            const f16x8* __restrict__ vp = (const f16x8*)v;
            // u32 index in f16x8 units: (b*Q_ + idx)*32 + h*4 + lane
            const unsigned vb = (bq >= Q_ ? (unsigned)Q_ * 32u : 0u)
                              + (unsigned)(h * 4 + lane);
            const float* __restrict__ offp  = off  + (size_t)bq * 256 + h * 32;
            const float* __restrict__ attnp = attn + (size_t)bq * 128 + h * 16;

            // softmax over 16 raw logits (exp2 form: 1 fma + 1 v_exp each)
            float aw[16];
            #pragma unroll
            for (int i = 0; i < 4; ++i) {
                const float4 x = *(const float4*)(attnp + i * 4);
                aw[i*4+0] = x.x; aw[i*4+1] = x.y; aw[i*4+2] = x.z; aw[i*4+3] = x.w;
            }
            float mx = aw[0];
            #pragma unroll
            for (int i = 1; i < 16; ++i) mx = fmaxf(mx, aw[i]);
            const float mb = mx * LOG2E;
            float sum = 0.f;
            #pragma unroll
            for (int i = 0; i < 16; ++i) {
                aw[i] = exp2f(fmaf(aw[i], LOG2E, -mb));
                sum += aw[i];
            }
            const float inv = 1.f / sum;
            #pragma unroll
            for (int i = 0; i < 16; ++i) aw[i] *= inv;

            const float4 r01 = *(const float4*)(ref + (size_t)bq * 8);
            const float4 r23 = *(const float4*)(ref + (size_t)bq * 8 + 4);
            const float rx[4] = {r01.x, r01.z, r23.x, r23.z};
            const float ry[4] = {r01.y, r01.w, r23.y, r23.w};

            #pragma unroll
            for (int l = 0; l < L_; ++l) {
                const float fW = (float)SW[l], fH = (float)SH[l];
                const int   Ww = SW[l], Hh = SH[l], st = ST[l];
                #pragma unroll
                for (int pp = 0; pp < 2; ++pp) {
                    const float4 o2 = *(const float4*)(offp + l * 8 + pp * 4);
                    #pragma unroll
                    for (int q = 0; q < 2; ++q) {
                        const int   p  = pp * 2 + q;
                        const float ox = q ? o2.z : o2.x;
                        const float oy = q ? o2.w : o2.y;
                        const float wA = aw[l * 4 + p];
                        const float gx = fmaf(rx[l], fW, ox) - 0.5f;
                        const float gy = fmaf(ry[l], fH, oy) - 0.5f;
                        const float x0f = floorf(gx), y0f = floorf(gy);
                        const int   x0  = (int)x0f,   y0  = (int)y0f;
                        const float wx1 = gx - x0f,   wy1 = gy - y0f;
                        const float wx0 = 1.f - wx1,  wy0 = 1.f - wy1;

                        const float mxw0 = ((unsigned)x0     < (unsigned)Ww) ? wx0 : 0.f;
                        const float mxw1 = ((unsigned)(x0+1) < (unsigned)Ww) ? wx1 : 0.f;
                        const float myw0 = ((unsigned)y0     < (unsigned)Hh) ? wy0 : 0.f;
                        const float myw1 = ((unsigned)(y0+1) < (unsigned)Hh) ? wy1 : 0.f;
                        const int xc0 = min(max(x0, 0),     Ww - 1);
                        const int xc1 = min(max(x0 + 1, 0), Ww - 1);
                        const int yc0 = min(max(y0, 0),     Hh - 1);
                        const int yc1 = min(max(y0 + 1, 0), Hh - 1);

                        const float w00 = wA * mxw0 * myw0;
                        const float w10 = wA * mxw1 * myw0;
                        const float w01 = wA * mxw0 * myw1;
                        const float w11 = wA * mxw1 * myw1;

                        const unsigned r0 = (unsigned)(st + yc0 * Ww);
                        const unsigned r1 = (unsigned)(st + yc1 * Ww);
                        const f16x8 s00 = vp[vb + (r0 + (unsigned)xc0) * 32u];
                        const f16x8 s10 = vp[vb + (r0 + (unsigned)xc1) * 32u];
                        const f16x8 s01 = vp[vb + (r1 + (unsigned)xc0) * 32u];
                        const f16x8 s11 = vp[vb + (r1 + (unsigned)xc1) * 32u];

                        #pragma unroll
                        for (int c = 0; c < 8; ++c) {
                            acc[c] = fmaf(w00, (float)s00[c], acc[c]);
                            acc[c] = fmaf(w10, (float)s10[c], acc[c]);
                            acc[c] = fmaf(w01, (float)s01[c], acc[c]);
                            acc[c] = fmaf(w11, (float)s11[c], acc[c]);
                        }
                    }
                }
            }
        }

        f16x8 o;
        #pragma unroll
        for (int c = 0; c < 8; ++c) o[c] = (f16_t)acc[c];
        *(f16x8*)&Samp[qi][h * 32 + lane * 8] = o;
    }

    __syncthreads();

    // ---------------- output projection: 16x256 @ WoT^T (frag-order B) ----
    const int lane = t & 63;
    const int w    = t >> 6;              // wave -> n-range w*64..+63
    const int quad = lane >> 4, l16 = lane & 15;

    f16x8 af[8];
    #pragma unroll
    for (int kf = 0; kf < 8; ++kf)
        af[kf] = *(const f16x8*)&Samp[l16][kf * 32 + quad * 8];

    f32x4 acc4[4];
    #pragma unroll
    for (int j = 0; j < 4; ++j) {
        f32x4 z = {0.f, 0.f, 0.f, 0.f};
        acc4[j] = z;
    }

    __builtin_amdgcn_s_setprio(1);
    #pragma unroll
    for (int j = 0; j < 4; ++j) {
        const int nf = w * 4 + j;
        const f16_t* bp = WoT + (size_t)nf * 4096 + lane * 8;
        #pragma unroll
        for (int kf = 0; kf < 8; ++kf) {
            const f16x8 bfr = *(const f16x8*)(bp + kf * 512);
            acc4[j] = __builtin_amdgcn_mfma_f32_16x16x32_f16(af[kf], bfr, acc4[j], 0, 0, 0);
        }
    }
    __builtin_amdgcn_s_setprio(0);

    #pragma unroll
    for (int j = 0; j < 4; ++j) {
        const int n  = w * 64 + j * 16 + l16;
        const float bv = b_out[n];
        #pragma unroll
        for (int r = 0; r < 4; ++r) {
            const int gm = bq0 + quad * 4 + r;
            if (gm < BQ)
                out[(size_t)gm * 256 + n] = acc4[j][r] + bv;
        }
    }
}

// ---------------------------------------------------------------------------
extern "C" void kernel_launch(void* const* d_in, const int* in_sizes, int n_in,
                              void* d_out, int out_size, void* d_ws, size_t ws_size,
                              hipStream_t stream)
{
    const float* query  = (const float*)d_in[0];
    const float* value  = (const float*)d_in[1];
    const float* refpts = (const float*)d_in[2];
    const float* w_off  = (const float*)d_in[4];
    const float* b_off  = (const float*)d_in[5];
    const float* w_attn = (const float*)d_in[6];
    const float* b_attn = (const float*)d_in[7];
    const float* w_val  = (const float*)d_in[8];
    const float* b_val  = (const float*)d_in[9];
    const float* w_out  = (const float*)d_in[10];
    const float* b_out  = (const float*)d_in[11];
    float* out = (float*)d_out;

    const int BQ = B_ * Q_;            // 39894

    // workspace layout
    char* ws = (char*)d_ws;
    f16_t* v_proj = (f16_t*)ws;                       ws += (size_t)BQ * 256 * 2;
    float* off_b  = (float*)ws;                       ws += (size_t)BQ * 256 * 4;
    float* attn_b = (float*)ws;                       ws += (size_t)BQ * 128 * 4;
    f16_t* WtV    = (f16_t*)ws;                       ws += (size_t)256 * 256 * 2;
    f16_t* WtQ    = (f16_t*)ws;                       ws += (size_t)384 * 256 * 2;
    f16_t* WtO    = (f16_t*)ws;

    const dim3 blk(256);

    // 0) all weight transposes -> fragment-order fp16, one dispatch
    transpose_all<<<dim3(8, 8, 4), blk, 0, stream>>>(w_val, w_off, w_attn, w_out,
                                                     WtV, WtQ, WtO);

    const int mg32 = (BQ + 31) / 32;   // 1247

    // 1) input projections: BM=32, A read once, coalesced frag-order B
    gemm_proj<<<dim3(mg32, 2), blk, 0, stream>>>(
        value, query, WtV, WtQ, b_val, b_off, b_attn,
        v_proj, off_b, attn_b, BQ);

    // 2) fused softmax + sampling + output projection -> d_out
    const int mg16 = (BQ + 15) / 16;   // 2494
    msda_fused<<<dim3(mg16), blk, 0, stream>>>(
        v_proj, off_b, attn_b, refpts, WtO, b_out, out, BQ);
}

// Round 11
// 253.206 us; speedup vs baseline: 2.9487x; 1.1090x over previous
//
#include <hip/hip_runtime.h>
#include <math.h>

// ---------------- problem constants (fixed by setup_inputs) ----------------
#define B_    2
#define Q_    19947
#define E_    256
#define H_    8
#define D_    32
#define L_    4
#define P_    4

typedef _Float16 f16_t;
typedef f16_t f16x8 __attribute__((ext_vector_type(8)));
typedef f16_t f16x4 __attribute__((ext_vector_type(4)));
typedef float f32x4 __attribute__((ext_vector_type(4)));

// ---------------------------------------------------------------------------
// Weight transpose + fp16 convert + MFMA-fragment-order swizzle (unchanged).
//   elem index = (nf*8 + kf)*512 + (quad*16 + l16)*8 + e
// z: 0=w_val->WtV(256) 1=w_off->WtQ(256) 2=w_attn->WtQ+64K(128) 3=w_out->WtO(256)
// ---------------------------------------------------------------------------
__global__ __launch_bounds__(256)
void transpose_all(const float* __restrict__ w_val, const float* __restrict__ w_off,
                   const float* __restrict__ w_attn, const float* __restrict__ w_out,
                   f16_t* __restrict__ WtV, f16_t* __restrict__ WtQ,
                   f16_t* __restrict__ WtO)
{
    const float* in; f16_t* out; int N;
    switch (blockIdx.z) {
        case 0:  in = w_val;  out = WtV;             N = 256; break;
        case 1:  in = w_off;  out = WtQ;             N = 256; break;
        case 2:  in = w_attn; out = WtQ + 256 * 256; N = 128; break;
        default: in = w_out;  out = WtO;             N = 256; break;
    }
    const int nt = blockIdx.x * 32;
    if (nt >= N) return;
    const int kt = blockIdx.y * 32;          // k-tile (multiple of 32 -> kf fixed)

    __shared__ float tile[32][33];
    const int x  = threadIdx.x & 31;
    const int y0 = threadIdx.x >> 5;          // 0..7
    #pragma unroll
    for (int p = 0; p < 4; ++p)
        tile[y0 + p * 8][x] = in[(size_t)(kt + y0 + p * 8) * N + nt + x];
    __syncthreads();
    const int kf = kt >> 5;
    #pragma unroll
    for (int p = 0; p < 4; ++p) {
        const int n    = nt + y0 + p * 8;
        const int nf   = n >> 4, l16 = n & 15;
        const int quad = (x >> 3) & 3, e = x & 7;
        out[(size_t)(nf * 8 + kf) * 512 + (quad * 16 + l16) * 8 + e]
            = (f16_t)tile[x][y0 + p * 8];
    }
}

// ---------------------------------------------------------------------------
// VALUE projection only (query projection moved into msda_fused).
// BM=32 row-tile, round-3-proven structure, byte-identical math:
// A staged once (17 KB LDS, one barrier), A-frags in 64 VGPRs, B streamed
// from L2 in fragment order (1 KB coalesced wave-loads), no loop barriers.
// v_proj layout (s, h*32+d): one 512-B row serves all 8 heads of a sample
// (heads sample near-identical pixels; r8 falsified per-head layout).
// ---------------------------------------------------------------------------
__global__ __launch_bounds__(256, 4)
void gemm_val(const float* __restrict__ Aval, const f16_t* __restrict__ WtV,
              const float* __restrict__ b_val,
              f16_t* __restrict__ v_proj, int M)
{
    __shared__ __align__(16) f16_t As[32][264];   // pad 8 f16 per row

    const int t  = threadIdx.x;
    const int m0 = blockIdx.x * 32;

    // ---- stage A: 32 rows x 256 fp32 -> fp16 LDS (thread: 1 row x 32 cols)
    {
        const int r  = t >> 3;            // 0..31
        const int c0 = (t & 7) * 32;      // 0..224
        const int gm = m0 + r;
        #pragma unroll
        for (int u = 0; u < 2; ++u) {
            f16_t tmp[16];
            if (gm < M) {
                #pragma unroll
                for (int q = 0; q < 4; ++q) {
                    const float4 v4 = *(const float4*)(Aval + (size_t)gm * 256 + c0 + u * 16 + q * 4);
                    tmp[q*4+0] = (f16_t)v4.x; tmp[q*4+1] = (f16_t)v4.y;
                    tmp[q*4+2] = (f16_t)v4.z; tmp[q*4+3] = (f16_t)v4.w;
                }
            } else {
                #pragma unroll
                for (int q = 0; q < 16; ++q) tmp[q] = (f16_t)0.f;
            }
            *(f16x8*)&As[r][c0 + u * 16]     = *(const f16x8*)&tmp[0];
            *(f16x8*)&As[r][c0 + u * 16 + 8] = *(const f16x8*)&tmp[8];
        }
    }
    __syncthreads();

    const int lane = t & 63;
    const int w    = t >> 6;
    const int quad = lane >> 4, l16 = lane & 15;

    // A fragments: 2 m-frags x full 256 k in registers (16 x f16x8 = 64 VGPRs)
    f16x8 af[2][8];
    #pragma unroll
    for (int mi = 0; mi < 2; ++mi)
        #pragma unroll
        for (int kf = 0; kf < 8; ++kf)
            af[mi][kf] = *(const f16x8*)&As[mi * 16 + l16][kf * 32 + quad * 8];

    // ---- MFMA loop: B fragment-order coalesced loads, no barriers
    #pragma unroll
    for (int j = 0; j < 4; ++j) {
        const int nf = w * 4 + j;
        const f16_t* __restrict__ bp = WtV + (size_t)nf * 4096 + lane * 8;

        f32x4 acc0 = {0.f, 0.f, 0.f, 0.f};
        f32x4 acc1 = {0.f, 0.f, 0.f, 0.f};
        #pragma unroll
        for (int kf = 0; kf < 8; ++kf) {
            const f16x8 bfr = *(const f16x8*)(bp + kf * 512);
            acc0 = __builtin_amdgcn_mfma_f32_16x16x32_f16(af[0][kf], bfr, acc0, 0, 0, 0);
            acc1 = __builtin_amdgcn_mfma_f32_16x16x32_f16(af[1][kf], bfr, acc1, 0, 0, 0);
        }

        const int n  = nf * 16 + l16;     // global output col
        const float bv = b_val[n];
        #pragma unroll
        for (int r = 0; r < 4; ++r) {
            const int gm0 = m0 + quad * 4 + r;
            const int gm1 = gm0 + 16;
            if (gm0 < M) v_proj[(size_t)gm0 * 256 + n] = (f16_t)(acc0[r] + bv);
            if (gm1 < M) v_proj[(size_t)gm1 * 256 + n] = (f16_t)(acc1[r] + bv);
        }
    }
}

// ---------------------------------------------------------------------------
// fused QUERY-PROJECTION + softmax + bilinear sampling + OUTPUT PROJECTION.
// Each block owns 16 queries:
//   phase 0: stage 16 query rows fp32->fp16 into AS (8.4 KB)
//   phase 1: 16x384 off/attn GEMM (same MFMA structure as tail) -> OffAtn LDS
//            (fp32, bit-identical to the old gemm_proj y=1 path)
//   phase 2: sampling (r9-proven body; off/attn read from LDS, not HBM)
//            Samp tile written into AS (union; A-stage dead after phase 1)
//   phase 3: 16x256 @ Wo^T MFMA tail (r9-proven)
// Removes 122 MB of off/attn HBM round-trip + 60% of the old gemm_proj.
// LDS 33.5 KB -> 4 blocks/CU.
// ---------------------------------------------------------------------------
__global__ __launch_bounds__(256, 4)
void msda_fused(const f16_t* __restrict__ v,      // (B, S, 256) fp16
                const float* __restrict__ Aqry,   // (B*Q, 256) fp32 query
                const f16_t* __restrict__ WtQ,    // frag-order, 24 nf
                const float* __restrict__ b_off,
                const float* __restrict__ b_attn,
                const float* __restrict__ ref,    // (B*Q, L, 2)
                const f16_t* __restrict__ WoT,    // frag-order, 16 nf
                const float* __restrict__ b_out,
                float* __restrict__ out,          // (B*Q, 256) fp32
                int BQ)
{
    constexpr int SH[4] = {100, 50, 25, 13};
    constexpr int SW[4] = {150, 75, 38, 19};
    constexpr int ST[4] = {0, 15000, 18750, 19700};
    constexpr float LOG2E = 1.4426950408889634f;

    __shared__ __align__(16) float OffAtn[16][392];  // cols 0..255 off, 256..383 attn
    __shared__ __align__(16) f16_t AS[16][264];      // A-stage, then Samp

    const int t   = threadIdx.x;
    const int bq0 = blockIdx.x * 16;

    // ---- phase 0: stage 16 query rows fp32 -> fp16 (thread: 1 row x 16 col)
    {
        const int r  = t >> 4;            // 0..15
        const int c0 = (t & 15) * 16;     // 0..240
        const int gm = bq0 + r;
        f16_t tmp[16];
        if (gm < BQ) {
            #pragma unroll
            for (int u = 0; u < 4; ++u) {
                const float4 v4 = *(const float4*)(Aqry + (size_t)gm * 256 + c0 + u * 4);
                tmp[u*4+0] = (f16_t)v4.x; tmp[u*4+1] = (f16_t)v4.y;
                tmp[u*4+2] = (f16_t)v4.z; tmp[u*4+3] = (f16_t)v4.w;
            }
        } else {
            #pragma unroll
            for (int u = 0; u < 16; ++u) tmp[u] = (f16_t)0.f;
        }
        *(f16x8*)&AS[r][c0]     = *(const f16x8*)&tmp[0];
        *(f16x8*)&AS[r][c0 + 8] = *(const f16x8*)&tmp[8];
    }
    __syncthreads();

    // ---- phase 1: 16x384 off/attn projection -> OffAtn (fp32 LDS) ----
    {
        const int lane = t & 63;
        const int w    = t >> 6;
        const int quad = lane >> 4, l16 = lane & 15;

        f16x8 af[8];
        #pragma unroll
        for (int kf = 0; kf < 8; ++kf)
            af[kf] = *(const f16x8*)&AS[l16][kf * 32 + quad * 8];

        __builtin_amdgcn_s_setprio(1);
        #pragma unroll
        for (int j = 0; j < 6; ++j) {
            const int nf = w * 6 + j;                 // 0..23
            const f16_t* __restrict__ bp = WtQ + (size_t)nf * 4096 + lane * 8;
            f32x4 a4 = {0.f, 0.f, 0.f, 0.f};
            #pragma unroll
            for (int kf = 0; kf < 8; ++kf) {
                const f16x8 bfr = *(const f16x8*)(bp + kf * 512);
                a4 = __builtin_amdgcn_mfma_f32_16x16x32_f16(af[kf], bfr, a4, 0, 0, 0);
            }
            const int n  = nf * 16 + l16;             // 0..383
            const float bv = (n < 256) ? b_off[n] : b_attn[n - 256];
            #pragma unroll
            for (int r = 0; r < 4; ++r)
                OffAtn[quad * 4 + r][n] = a4[r] + bv;
        }
        __builtin_amdgcn_s_setprio(0);
    }
    __syncthreads();

    // ---- phase 2: sampling, 2 rounds of 8 queries (r9-proven body) ----
    #pragma unroll
    for (int r = 0; r < 2; ++r) {
        const int g    = t >> 2;                 // 0..63
        const int qi   = (g >> 3) + r * 8;       // 0..15
        const int h    = g & 7;
        const int lane = t & 3;
        const int bq   = bq0 + qi;

        float acc[8] = {0.f, 0.f, 0.f, 0.f, 0.f, 0.f, 0.f, 0.f};

        if (bq < BQ) {
            const f16x8* __restrict__ vp = (const f16x8*)v;
            // u32 index in f16x8 units: (b*Q_ + idx)*32 + h*4 + lane
            const unsigned vb = (bq >= Q_ ? (unsigned)Q_ * 32u : 0u)
                              + (unsigned)(h * 4 + lane);

            // softmax over 16 raw logits from LDS (exp2 form)
            float aw[16];
            #pragma unroll
            for (int i = 0; i < 4; ++i) {
                const float4 x = *(const float4*)&OffAtn[qi][256 + h * 16 + i * 4];
                aw[i*4+0] = x.x; aw[i*4+1] = x.y; aw[i*4+2] = x.z; aw[i*4+3] = x.w;
            }
            float mx = aw[0];
            #pragma unroll
            for (int i = 1; i < 16; ++i) mx = fmaxf(mx, aw[i]);
            const float mb = mx * LOG2E;
            float sum = 0.f;
            #pragma unroll
            for (int i = 0; i < 16; ++i) {
                aw[i] = exp2f(fmaf(aw[i], LOG2E, -mb));
                sum += aw[i];
            }
            const float inv = 1.f / sum;
            #pragma unroll
            for (int i = 0; i < 16; ++i) aw[i] *= inv;

            const float4 r01 = *(const float4*)(ref + (size_t)bq * 8);
            const float4 r23 = *(const float4*)(ref + (size_t)bq * 8 + 4);
            const float rx[4] = {r01.x, r01.z, r23.x, r23.z};
            const float ry[4] = {r01.y, r01.w, r23.y, r23.w};

            #pragma unroll
            for (int l = 0; l < L_; ++l) {
                const float fW = (float)SW[l], fH = (float)SH[l];
                const int   Ww = SW[l], Hh = SH[l], st = ST[l];
                #pragma unroll
                for (int pp = 0; pp < 2; ++pp) {
                    const float4 o2 = *(const float4*)&OffAtn[qi][h * 32 + l * 8 + pp * 4];
                    #pragma unroll
                    for (int q = 0; q < 2; ++q) {
                        const int   p  = pp * 2 + q;
                        const float ox = q ? o2.z : o2.x;
                        const float oy = q ? o2.w : o2.y;
                        const float wA = aw[l * 4 + p];
                        const float gx = fmaf(rx[l], fW, ox) - 0.5f;
                        const float gy = fmaf(ry[l], fH, oy) - 0.5f;
                        const float x0f = floorf(gx), y0f = floorf(gy);
                        const int   x0  = (int)x0f,   y0  = (int)y0f;
                        const float wx1 = gx - x0f,   wy1 = gy - y0f;
                        const float wx0 = 1.f - wx1,  wy0 = 1.f - wy1;

                        const float mxw0 = ((unsigned)x0     < (unsigned)Ww) ? wx0 : 0.f;
                        const float mxw1 = ((unsigned)(x0+1) < (unsigned)Ww) ? wx1 : 0.f;
                        const float myw0 = ((unsigned)y0     < (unsigned)Hh) ? wy0 : 0.f;
                        const float myw1 = ((unsigned)(y0+1) < (unsigned)Hh) ? wy1 : 0.f;
                        const int xc0 = min(max(x0, 0),     Ww - 1);
                        const int xc1 = min(max(x0 + 1, 0), Ww - 1);
                        const int yc0 = min(max(y0, 0),     Hh - 1);
                        const int yc1 = min(max(y0 + 1, 0), Hh - 1);

                        const float w00 = wA * mxw0 * myw0;
                        const float w10 = wA * mxw1 * myw0;
                        const float w01 = wA * mxw0 * myw1;
                        const float w11 = wA * mxw1 * myw1;

                        const unsigned r0 = (unsigned)(st + yc0 * Ww);
                        const unsigned r1 = (unsigned)(st + yc1 * Ww);
                        const f16x8 s00 = vp[vb + (r0 + (unsigned)xc0) * 32u];
                        const f16x8 s10 = vp[vb + (r0 + (unsigned)xc1) * 32u];
                        const f16x8 s01 = vp[vb + (r1 + (unsigned)xc0) * 32u];
                        const f16x8 s11 = vp[vb + (r1 + (unsigned)xc1) * 32u];

                        #pragma unroll
                        for (int c = 0; c < 8; ++c) {
                            acc[c] = fmaf(w00, (float)s00[c], acc[c]);
                            acc[c] = fmaf(w10, (float)s10[c], acc[c]);
                            acc[c] = fmaf(w01, (float)s01[c], acc[c]);
                            acc[c] = fmaf(w11, (float)s11[c], acc[c]);
                        }
                    }
                }
            }
        }

        f16x8 o;
        #pragma unroll
        for (int c = 0; c < 8; ++c) o[c] = (f16_t)acc[c];
        *(f16x8*)&AS[qi][h * 32 + lane * 8] = o;    // AS reused as Samp
    }

    __syncthreads();

    // ---- phase 3: output projection 16x256 @ WoT^T (frag-order B) ----
    const int lane = t & 63;
    const int w    = t >> 6;              // wave -> n-range w*64..+63
    const int quad = lane >> 4, l16 = lane & 15;

    f16x8 af[8];
    #pragma unroll
    for (int kf = 0; kf < 8; ++kf)
        af[kf] = *(const f16x8*)&AS[l16][kf * 32 + quad * 8];

    f32x4 acc4[4];
    #pragma unroll
    for (int j = 0; j < 4; ++j) {
        f32x4 z = {0.f, 0.f, 0.f, 0.f};
        acc4[j] = z;
    }

    __builtin_amdgcn_s_setprio(1);
    #pragma unroll
    for (int j = 0; j < 4; ++j) {
        const int nf = w * 4 + j;
        const f16_t* bp = WoT + (size_t)nf * 4096 + lane * 8;
        #pragma unroll
        for (int kf = 0; kf < 8; ++kf) {
            const f16x8 bfr = *(const f16x8*)(bp + kf * 512);
            acc4[j] = __builtin_amdgcn_mfma_f32_16x16x32_f16(af[kf], bfr, acc4[j], 0, 0, 0);
        }
    }
    __builtin_amdgcn_s_setprio(0);

    #pragma unroll
    for (int j = 0; j < 4; ++j) {
        const int n  = w * 64 + j * 16 + l16;
        const float bv = b_out[n];
        #pragma unroll
        for (int r = 0; r < 4; ++r) {
            const int gm = bq0 + quad * 4 + r;
            if (gm < BQ)
                out[(size_t)gm * 256 + n] = acc4[j][r] + bv;
        }
    }
}

// ---------------------------------------------------------------------------
extern "C" void kernel_launch(void* const* d_in, const int* in_sizes, int n_in,
                              void* d_out, int out_size, void* d_ws, size_t ws_size,
                              hipStream_t stream)
{
    const float* query  = (const float*)d_in[0];
    const float* value  = (const float*)d_in[1];
    const float* refpts = (const float*)d_in[2];
    const float* w_off  = (const float*)d_in[4];
    const float* b_off  = (const float*)d_in[5];
    const float* w_attn = (const float*)d_in[6];
    const float* b_attn = (const float*)d_in[7];
    const float* w_val  = (const float*)d_in[8];
    const float* b_val  = (const float*)d_in[9];
    const float* w_out  = (const float*)d_in[10];
    const float* b_out  = (const float*)d_in[11];
    float* out = (float*)d_out;

    const int BQ = B_ * Q_;            // 39894

    // workspace layout
    char* ws = (char*)d_ws;
    f16_t* v_proj = (f16_t*)ws;                       ws += (size_t)BQ * 256 * 2;
    f16_t* WtV    = (f16_t*)ws;                       ws += (size_t)256 * 256 * 2;
    f16_t* WtQ    = (f16_t*)ws;                       ws += (size_t)384 * 256 * 2;
    f16_t* WtO    = (f16_t*)ws;

    const dim3 blk(256);

    // 0) all weight transposes -> fragment-order fp16, one dispatch
    transpose_all<<<dim3(8, 8, 4), blk, 0, stream>>>(w_val, w_off, w_attn, w_out,
                                                     WtV, WtQ, WtO);

    const int mg32 = (BQ + 31) / 32;   // 1247

    // 1) value projection only (query projection fused into msda)
    gemm_val<<<dim3(mg32), blk, 0, stream>>>(value, WtV, b_val, v_proj, BQ);

    // 2) fused query-proj + softmax + sampling + output projection -> d_out
    const int mg16 = (BQ + 15) / 16;   // 2494
    msda_fused<<<dim3(mg16), blk, 0, stream>>>(
        v_proj, query, WtQ, b_off, b_attn, refpts, WtO, b_out, out, BQ);
}